// Round 2
// baseline (955.510 us; speedup 1.0000x reference)
//
#include <hip/hip_runtime.h>
#include <stdint.h>

#define BATCH 4
#define HEADS 16
#define SEQ   2048
#define DIM   128

typedef short short8 __attribute__((ext_vector_type(8)));
typedef float floatx4 __attribute__((ext_vector_type(4)));
typedef uint32_t uint2v __attribute__((ext_vector_type(2)));

// LDS strides in bf16 elements (padded; 8B/16B alignment preserved)
#define KT_STRIDE 136   // 128 + 8
#define VT_STRIDE 40    // 32 + 8
#define P_STRIDE  40    // 32 + 8

// 1/sqrt(128) * log2(e): softmax in base-2 domain
#define QK_SCALE_LOG2E 0.1274750709470246f

__device__ __forceinline__ ushort f2bf_rn(float f) {
    union { float f; uint32_t u; } x; x.f = f;
    return (ushort)((x.u + 0x8000u) >> 16);
}
// pack bf16(f0) into low 16, bf16(f1) into high 16 (round-to-nearest via +0x8000)
__device__ __forceinline__ uint32_t pack_bf16x2(float f0, float f1) {
    union { float f; uint32_t u; } a, b; a.f = f0; b.f = f1;
    return __builtin_amdgcn_perm(b.u + 0x8000u, a.u + 0x8000u, 0x07060302u);
}

__global__ __launch_bounds__(256)
void fa_fwd(const float* __restrict__ Q, const float* __restrict__ K,
            const float* __restrict__ V, float* __restrict__ O)
{
    // heavy tiles (large qt) first to reduce tail effect
    const int qt = gridDim.x - 1 - blockIdx.x;   // q-tile index, 64 rows each
    const int bh = blockIdx.y;
    const int qb = qt * 64;
    const size_t hb = (size_t)bh * SEQ * DIM;

    const int tid  = threadIdx.x;
    const int wave = tid >> 6;
    const int lane = tid & 63;
    const int l15  = lane & 15;
    const int q4   = lane >> 4;

    __shared__ ushort lds_k [32 * KT_STRIDE];
    __shared__ ushort lds_vt[128 * VT_STRIDE];   // V transposed: [d][key]
    __shared__ ushort lds_p [4 * 16 * P_STRIDE]; // per-wave P scratch

    // ---- Q fragments (A-layout: A[m=lane&15][k=q4*8+j]), f32 -> bf16, in registers
    const int wrow0 = qb + wave * 16;
    const int qrow  = wrow0 + l15;
    short8 qf[4];
    {
        const float* qp = Q + hb + (size_t)qrow * DIM + q4 * 8;
        #pragma unroll
        for (int kk = 0; kk < 4; ++kk) {
            float4 a = *(const float4*)(qp + kk * 32);
            float4 b = *(const float4*)(qp + kk * 32 + 4);
            union { short8 s; uint32_t u[4]; } t;
            t.u[0] = pack_bf16x2(a.x, a.y);
            t.u[1] = pack_bf16x2(a.z, a.w);
            t.u[2] = pack_bf16x2(b.x, b.y);
            t.u[3] = pack_bf16x2(b.z, b.w);
            qf[kk] = t.s;
        }
    }

    floatx4 o_acc[8];
    #pragma unroll
    for (int t = 0; t < 8; ++t) o_acc[t] = (floatx4){0.f, 0.f, 0.f, 0.f};
    float m_i[4], l_i[4];
    #pragma unroll
    for (int r = 0; r < 4; ++r) { m_i[r] = -1e38f; l_i[r] = 0.f; }

    const int kend = qb + 64;
    for (int kb = 0; kb < kend; kb += 32) {
        __syncthreads();   // previous iteration's LDS reads complete
        // ---- stage K tile [32][128] and V tile transposed [128][32], f32 -> bf16
        #pragma unroll
        for (int i = 0; i < 4; ++i) {
            const int c   = tid + i * 256;     // 0..1023 chunks of 4 floats
            const int row = c >> 5;            // 0..31
            const int dch = (c & 31) * 4;      // 0..124
            const size_t g = hb + (size_t)(kb + row) * DIM + dch;
            float4 kd = *(const float4*)(K + g);
            uint2v kp; kp.x = pack_bf16x2(kd.x, kd.y); kp.y = pack_bf16x2(kd.z, kd.w);
            *(uint2v*)(&lds_k[row * KT_STRIDE + dch]) = kp;
            float4 vd = *(const float4*)(V + g);
            ushort* vt = &lds_vt[dch * VT_STRIDE + row];
            vt[0 * VT_STRIDE] = f2bf_rn(vd.x);
            vt[1 * VT_STRIDE] = f2bf_rn(vd.y);
            vt[2 * VT_STRIDE] = f2bf_rn(vd.z);
            vt[3 * VT_STRIDE] = f2bf_rn(vd.w);
        }
        __syncthreads();

        // skip tiles entirely above the diagonal for this wave (wave-uniform)
        if (kb > wrow0 + 15) continue;

        // ---- QK^T: two 16-col subtiles, K-dim = 128 via 4 MFMAs each
        floatx4 s0 = (floatx4){0.f,0.f,0.f,0.f};
        floatx4 s1 = (floatx4){0.f,0.f,0.f,0.f};
        #pragma unroll
        for (int kk = 0; kk < 4; ++kk) {
            short8 b0 = *(const short8*)(&lds_k[l15 * KT_STRIDE + kk * 32 + q4 * 8]);
            short8 b1 = *(const short8*)(&lds_k[(16 + l15) * KT_STRIDE + kk * 32 + q4 * 8]);
            s0 = __builtin_amdgcn_mfma_f32_16x16x32_bf16(qf[kk], b0, s0, 0, 0, 0);
            s1 = __builtin_amdgcn_mfma_f32_16x16x32_bf16(qf[kk], b1, s1, 0, 0, 0);
        }

        // ---- scale + causal mask + online softmax (base-2)
        const int col0 = kb + l15;
        const int col1 = kb + 16 + l15;
        float mx[4];
        #pragma unroll
        for (int r = 0; r < 4; ++r) {
            const int rg = wrow0 + q4 * 4 + r;
            float a = s0[r] * QK_SCALE_LOG2E;
            float b = s1[r] * QK_SCALE_LOG2E;
            a = (col0 <= rg) ? a : -1e38f;
            b = (col1 <= rg) ? b : -1e38f;
            s0[r] = a; s1[r] = b;
            mx[r] = fmaxf(a, b);
        }
        #pragma unroll
        for (int r = 0; r < 4; ++r) {       // row-max across the 16 C-layout lanes
            float v = mx[r];
            v = fmaxf(v, __shfl_xor(v, 1));
            v = fmaxf(v, __shfl_xor(v, 2));
            v = fmaxf(v, __shfl_xor(v, 4));
            v = fmaxf(v, __shfl_xor(v, 8));
            mx[r] = v;
        }
        float alpha[4], rsum[4];
        #pragma unroll
        for (int r = 0; r < 4; ++r) {
            const float mnew = fmaxf(m_i[r], mx[r]);
            alpha[r] = __builtin_amdgcn_exp2f(m_i[r] - mnew);
            m_i[r] = mnew;
            const float pa = __builtin_amdgcn_exp2f(s0[r] - mnew);
            const float pb = __builtin_amdgcn_exp2f(s1[r] - mnew);
            s0[r] = pa; s1[r] = pb;
            rsum[r] = pa + pb;
        }
        #pragma unroll
        for (int r = 0; r < 4; ++r) {       // row-sum across the 16 C-layout lanes
            float v = rsum[r];
            v += __shfl_xor(v, 1);
            v += __shfl_xor(v, 2);
            v += __shfl_xor(v, 4);
            v += __shfl_xor(v, 8);
            l_i[r] = l_i[r] * alpha[r] + v;
        }
        #pragma unroll
        for (int t = 0; t < 8; ++t)
            #pragma unroll
            for (int r = 0; r < 4; ++r)
                o_acc[t][r] *= alpha[r];

        // ---- P: C-layout -> LDS -> A-layout (m120-verified transform)
        ushort* pw = &lds_p[wave * 16 * P_STRIDE];
        #pragma unroll
        for (int r = 0; r < 4; ++r) {
            const int prow = q4 * 4 + r;
            pw[prow * P_STRIDE + l15]      = f2bf_rn(s0[r]);
            pw[prow * P_STRIDE + 16 + l15] = f2bf_rn(s1[r]);
        }
        asm volatile("s_waitcnt lgkmcnt(0)" ::: "memory"); // wave-local RAW on lds_p
        const short8 pf = *(const short8*)(&pw[l15 * P_STRIDE + q4 * 8]);

        // ---- PV: K-dim = 32 keys, 8 subtiles over D=128
        #pragma unroll
        for (int t = 0; t < 8; ++t) {
            short8 vf = *(const short8*)(&lds_vt[(t * 16 + l15) * VT_STRIDE + q4 * 8]);
            o_acc[t] = __builtin_amdgcn_mfma_f32_16x16x32_bf16(pf, vf, o_acc[t], 0, 0, 0);
        }
    }

    // ---- epilogue: O / l_i, write f32
    float inv[4];
    #pragma unroll
    for (int r = 0; r < 4; ++r) inv[r] = __builtin_amdgcn_rcpf(l_i[r]);
    #pragma unroll
    for (int t = 0; t < 8; ++t) {
        #pragma unroll
        for (int r = 0; r < 4; ++r) {
            const int rg = wrow0 + q4 * 4 + r;
            O[hb + (size_t)rg * DIM + t * 16 + l15] = o_acc[t][r] * inv[r];
        }
    }
}

extern "C" void kernel_launch(void* const* d_in, const int* in_sizes, int n_in,
                              void* d_out, int out_size, void* d_ws, size_t ws_size,
                              hipStream_t stream) {
    const float* q = (const float*)d_in[0];
    const float* k = (const float*)d_in[1];
    const float* v = (const float*)d_in[2];
    float* o = (float*)d_out;
    dim3 grid(SEQ / 64, BATCH * HEADS);
    fa_fwd<<<grid, dim3(256), 0, stream>>>(q, k, v, o);
}

// Round 3
// 912.628 us; speedup vs baseline: 1.0470x; 1.0470x over previous
//
#include <hip/hip_runtime.h>
#include <stdint.h>

#define BATCH 4
#define HEADS 16
#define SEQ   2048
#define DIM   128
#define QROWS 64   // per block: 2 waves x 32 rows
#define BK    32

typedef short short8 __attribute__((ext_vector_type(8)));
typedef float floatx4 __attribute__((ext_vector_type(4)));

// 1/sqrt(128) * log2(e): softmax in base-2 domain
#define QK_SCALE_LOG2E 0.1274750709470246f

static __device__ __forceinline__ ushort f2bf_rn(float f) {
    union { float f; uint32_t u; } x; x.f = f;
    return (ushort)((x.u + 0x8000u) >> 16);
}
static __device__ __forceinline__ uint32_t pack_bf16x2(float f0, float f1) {
    union { float f; uint32_t u; } a, b; a.f = f0; b.f = f1;
    return __builtin_amdgcn_perm(b.u + 0x8000u, a.u + 0x8000u, 0x07060302u);
}

__global__ __launch_bounds__(128)
void fa_fwd(const float* __restrict__ Q, const float* __restrict__ K,
            const float* __restrict__ V, float* __restrict__ O)
{
    // heavy q-tiles first
    const int qt = gridDim.x - 1 - blockIdx.x;
    const int bh = blockIdx.y;
    const int qb = qt * QROWS;
    const size_t hb = (size_t)bh * SEQ * DIM;

    const int tid  = threadIdx.x;
    const int w    = tid >> 6;      // wave 0..1
    const int lane = tid & 63;
    const int l15  = lane & 15;
    const int q4   = lane >> 4;

    // Fragment-order blobs: every access is b128 at lane*16B (conflict floor)
    __shared__ ushort kblob[8 * 64 * 8];     // [c*4+kk][lane][8]  = K[c*16+l15][kk*32+q4*8+j]
    __shared__ ushort vblob[8 * 64 * 8];     // [t][lane][8]       = V[q4*8+j][t*16+l15]
    __shared__ ushort pblob[2][2][64 * 8];   // [wave][h][m*8 + (k>>3)*128 + (k&7)]

    const int wrow0 = qb + w * 32;

    // ---- Q fragments (A-layout), f32->bf16, persistent in registers
    short8 qf[2][4];
    #pragma unroll
    for (int h = 0; h < 2; ++h) {
        const float* qp = Q + hb + (size_t)(wrow0 + h * 16 + l15) * DIM + q4 * 8;
        #pragma unroll
        for (int kk = 0; kk < 4; ++kk) {
            float4 a = *(const float4*)(qp + kk * 32);
            float4 b = *(const float4*)(qp + kk * 32 + 4);
            union { short8 s; uint32_t u[4]; } u_;
            u_.u[0] = pack_bf16x2(a.x, a.y);
            u_.u[1] = pack_bf16x2(a.z, a.w);
            u_.u[2] = pack_bf16x2(b.x, b.y);
            u_.u[3] = pack_bf16x2(b.z, b.w);
            qf[h][kk] = u_.s;
        }
    }

    floatx4 o_acc[2][8];
    float m_i[2][4], l_i[2][4];
    #pragma unroll
    for (int h = 0; h < 2; ++h) {
        #pragma unroll
        for (int t = 0; t < 8; ++t) o_acc[h][t] = (floatx4){0.f, 0.f, 0.f, 0.f};
        #pragma unroll
        for (int r = 0; r < 4; ++r) { m_i[h][r] = -1e38f; l_i[h][r] = 0.f; }
    }

    const int kend = qb + QROWS;
    for (int kb = 0; kb < kend; kb += BK) {
        __syncthreads();
        // ---- stage K tile into fragment blob (4 passes x 2 waves = 8 groups)
        #pragma unroll
        for (int p = 0; p < 4; ++p) {
            const int g  = p * 2 + w;       // 0..7
            const int c  = g >> 2;          // key half
            const int kk = g & 3;           // 32-wide k chunk
            const float* src = K + hb + (size_t)(kb + c * 16 + l15) * DIM + kk * 32 + q4 * 8;
            float4 a = *(const float4*)src;
            float4 b = *(const float4*)(src + 4);
            union { short8 s; uint32_t u[4]; } u_;
            u_.u[0] = pack_bf16x2(a.x, a.y);
            u_.u[1] = pack_bf16x2(a.z, a.w);
            u_.u[2] = pack_bf16x2(b.x, b.y);
            u_.u[3] = pack_bf16x2(b.z, b.w);
            *(short8*)(&kblob[(g * 64 + lane) * 8]) = u_.s;
        }
        // ---- stage V tile: transposed gather from global (coalesced 64B lines),
        //      b128 blob write
        #pragma unroll
        for (int p = 0; p < 4; ++p) {
            const int ts = p * 2 + w;       // d-subtile 0..7
            const float* src = V + hb + (size_t)(kb + q4 * 8) * DIM + ts * 16 + l15;
            float v0 = src[0 * DIM], v1 = src[1 * DIM], v2 = src[2 * DIM], v3 = src[3 * DIM];
            float v4 = src[4 * DIM], v5 = src[5 * DIM], v6 = src[6 * DIM], v7 = src[7 * DIM];
            union { short8 s; uint32_t u[4]; } u_;
            u_.u[0] = pack_bf16x2(v0, v1);
            u_.u[1] = pack_bf16x2(v2, v3);
            u_.u[2] = pack_bf16x2(v4, v5);
            u_.u[3] = pack_bf16x2(v6, v7);
            *(short8*)(&vblob[(ts * 64 + lane) * 8]) = u_.s;
        }
        __syncthreads();

        // wave-uniform skip of fully-masked tiles
        if (kb > wrow0 + 31) continue;

        // ---- QK^T: 2 m-subtiles x 2 col-subtiles, k=128 via 4 chained MFMAs
        floatx4 sc[2][2];
        sc[0][0] = (floatx4){0.f,0.f,0.f,0.f}; sc[0][1] = (floatx4){0.f,0.f,0.f,0.f};
        sc[1][0] = (floatx4){0.f,0.f,0.f,0.f}; sc[1][1] = (floatx4){0.f,0.f,0.f,0.f};
        #pragma unroll
        for (int kk = 0; kk < 4; ++kk) {
            short8 b0 = *(const short8*)(&kblob[((0 + kk) * 64 + lane) * 8]);
            short8 b1 = *(const short8*)(&kblob[((4 + kk) * 64 + lane) * 8]);
            sc[0][0] = __builtin_amdgcn_mfma_f32_16x16x32_bf16(qf[0][kk], b0, sc[0][0], 0, 0, 0);
            sc[0][1] = __builtin_amdgcn_mfma_f32_16x16x32_bf16(qf[0][kk], b1, sc[0][1], 0, 0, 0);
            sc[1][0] = __builtin_amdgcn_mfma_f32_16x16x32_bf16(qf[1][kk], b0, sc[1][0], 0, 0, 0);
            sc[1][1] = __builtin_amdgcn_mfma_f32_16x16x32_bf16(qf[1][kk], b1, sc[1][1], 0, 0, 0);
        }

        // ---- online softmax (base-2) per m-subtile
        #pragma unroll
        for (int h = 0; h < 2; ++h) {
            const int rbase = wrow0 + h * 16 + q4 * 4;
            const int col0 = kb + l15;
            const int col1 = kb + 16 + l15;
            float mx[4];
            #pragma unroll
            for (int r = 0; r < 4; ++r) {
                const int rg = rbase + r;
                float a = sc[h][0][r] * QK_SCALE_LOG2E;
                float b = sc[h][1][r] * QK_SCALE_LOG2E;
                a = (col0 <= rg) ? a : -1e38f;
                b = (col1 <= rg) ? b : -1e38f;
                sc[h][0][r] = a; sc[h][1][r] = b;
                mx[r] = fmaxf(a, b);
            }
            #pragma unroll
            for (int r = 0; r < 4; ++r) {
                float v = mx[r];
                v = fmaxf(v, __shfl_xor(v, 1));
                v = fmaxf(v, __shfl_xor(v, 2));
                v = fmaxf(v, __shfl_xor(v, 4));
                v = fmaxf(v, __shfl_xor(v, 8));
                mx[r] = v;
            }
            float alpha[4], rsum[4];
            #pragma unroll
            for (int r = 0; r < 4; ++r) {
                const float mnew = fmaxf(m_i[h][r], mx[r]);
                alpha[r] = __builtin_amdgcn_exp2f(m_i[h][r] - mnew);
                m_i[h][r] = mnew;
                const float pa = __builtin_amdgcn_exp2f(sc[h][0][r] - mnew);
                const float pb = __builtin_amdgcn_exp2f(sc[h][1][r] - mnew);
                sc[h][0][r] = pa; sc[h][1][r] = pb;
                rsum[r] = pa + pb;
            }
            #pragma unroll
            for (int r = 0; r < 4; ++r) {
                float v = rsum[r];
                v += __shfl_xor(v, 1);
                v += __shfl_xor(v, 2);
                v += __shfl_xor(v, 4);
                v += __shfl_xor(v, 8);
                l_i[h][r] = l_i[h][r] * alpha[r] + v;
            }
            // P: C-layout -> A-fragment blob (addr = m*8 + (k>>3)*128 + (k&7))
            ushort* pw = pblob[w][h];
            const int wo = (l15 >> 3) * 128 + (l15 & 7);
            #pragma unroll
            for (int r = 0; r < 4; ++r) {
                const int m = q4 * 4 + r;
                pw[m * 8 + wo]       = f2bf_rn(sc[h][0][r]);
                pw[m * 8 + wo + 256] = f2bf_rn(sc[h][1][r]);
            }
            #pragma unroll
            for (int t = 0; t < 8; ++t)
                #pragma unroll
                for (int r = 0; r < 4; ++r)
                    o_acc[h][t][r] *= alpha[r];
        }
        asm volatile("s_waitcnt lgkmcnt(0)" ::: "memory"); // wave-local RAW on pblob
        const short8 pf0 = *(const short8*)(&pblob[w][0][lane * 8]);
        const short8 pf1 = *(const short8*)(&pblob[w][1][lane * 8]);

        // ---- PV: V-fragments read once, used for both m-subtiles
        #pragma unroll
        for (int t = 0; t < 8; ++t) {
            short8 vf = *(const short8*)(&vblob[(t * 64 + lane) * 8]);
            o_acc[0][t] = __builtin_amdgcn_mfma_f32_16x16x32_bf16(pf0, vf, o_acc[0][t], 0, 0, 0);
            o_acc[1][t] = __builtin_amdgcn_mfma_f32_16x16x32_bf16(pf1, vf, o_acc[1][t], 0, 0, 0);
        }
    }

    // ---- epilogue: O = acc / l_i, f32 stores
    #pragma unroll
    for (int h = 0; h < 2; ++h) {
        float inv[4];
        #pragma unroll
        for (int r = 0; r < 4; ++r) inv[r] = __builtin_amdgcn_rcpf(l_i[h][r]);
        #pragma unroll
        for (int t = 0; t < 8; ++t) {
            #pragma unroll
            for (int r = 0; r < 4; ++r) {
                const int rg = wrow0 + h * 16 + q4 * 4 + r;
                O[hb + (size_t)rg * DIM + t * 16 + l15] = o_acc[h][t][r] * inv[r];
            }
        }
    }
}

extern "C" void kernel_launch(void* const* d_in, const int* in_sizes, int n_in,
                              void* d_out, int out_size, void* d_ws, size_t ws_size,
                              hipStream_t stream) {
    const float* q = (const float*)d_in[0];
    const float* k = (const float*)d_in[1];
    const float* v = (const float*)d_in[2];
    float* o = (float*)d_out;
    dim3 grid(SEQ / QROWS, BATCH * HEADS);
    fa_fwd<<<grid, dim3(128), 0, stream>>>(q, k, v, o);
}

// Round 4
// 601.267 us; speedup vs baseline: 1.5892x; 1.5178x over previous
//
#include <hip/hip_runtime.h>
#include <stdint.h>

#define BATCH 4
#define HEADS 16
#define SEQ   2048
#define DIM   128
#define QROWS 128   // per block: 4 waves, each owns rows qb+16w (h=0) and qb+64+16w (h=1)
#define BK    64

typedef short short8 __attribute__((ext_vector_type(8)));
typedef float floatx4 __attribute__((ext_vector_type(4)));

// 1/sqrt(128) * log2(e): softmax in base-2 domain
#define QK_SCALE_LOG2E 0.1274750709470246f

static __device__ __forceinline__ ushort f2bf_rn(float f) {
    union { float f; uint32_t u; } x; x.f = f;
    return (ushort)((x.u + 0x8000u) >> 16);
}
static __device__ __forceinline__ uint32_t pack_bf16x2(float f0, float f1) {
    union { float f; uint32_t u; } a, b; a.f = f0; b.f = f1;
    return __builtin_amdgcn_perm(b.u + 0x8000u, a.u + 0x8000u, 0x07060302u);
}

__global__ __launch_bounds__(256, 2)
void fa_fwd(const float* __restrict__ Q, const float* __restrict__ K,
            const float* __restrict__ V, float* __restrict__ O)
{
    const int qt = gridDim.x - 1 - blockIdx.x;   // heavy q-tiles first
    const int qb = qt * QROWS;
    const size_t hb = (size_t)blockIdx.y * SEQ * DIM;

    const int tid  = threadIdx.x;
    const int w    = tid >> 6;
    const int lane = tid & 63;
    const int l15  = lane & 15;
    const int q4   = lane >> 4;

    // Fragment-order blobs, double-buffered. Every access is b128 at lane*16B.
    // kblob group g=c*4+kk: elem = K[kb+c*16+l15][kk*32+q4*8+j]
    // vblob group g=t*2+kc: elem = V[kb+kc*32+q4*8+j][t*16+l15]
    __shared__ ushort kblob[2][16 * 64 * 8];
    __shared__ ushort vblob[2][16 * 64 * 8];
    __shared__ ushort pblob[4][2][2][64 * 8];   // [wave][h][kc][A-frag]

    const int row0[2] = { qb + w * 16, qb + 64 + w * 16 };

    // ---- Q fragments (A-layout), f32->bf16, persistent in registers
    short8 qf[2][4];
    #pragma unroll
    for (int h = 0; h < 2; ++h) {
        const float* qp = Q + hb + (size_t)(row0[h] + l15) * DIM + q4 * 8;
        #pragma unroll
        for (int kk = 0; kk < 4; ++kk) {
            float4 a = *(const float4*)(qp + kk * 32);
            float4 b = *(const float4*)(qp + kk * 32 + 4);
            union { short8 s; uint32_t u[4]; } u_;
            u_.u[0] = pack_bf16x2(a.x, a.y);
            u_.u[1] = pack_bf16x2(a.z, a.w);
            u_.u[2] = pack_bf16x2(b.x, b.y);
            u_.u[3] = pack_bf16x2(b.z, b.w);
            qf[h][kk] = u_.s;
        }
    }

    floatx4 o_acc[2][8];
    float m_i[2][4], l_i[2][4];
    #pragma unroll
    for (int h = 0; h < 2; ++h) {
        #pragma unroll
        for (int t = 0; t < 8; ++t) o_acc[h][t] = (floatx4){0.f, 0.f, 0.f, 0.f};
        #pragma unroll
        for (int r = 0; r < 4; ++r) { m_i[h][r] = -1e38f; l_i[h][r] = 0.f; }
    }

    // ---- staging registers (prefetch pipeline)
    float4 kr[4][2];
    float  vr[4][8];

    auto issue = [&](int kb) {
        #pragma unroll
        for (int p = 0; p < 4; ++p) {
            const int g = p * 4 + w;            // K: c=p, kk=w; V: t=g>>1, kc=g&1
            const float* ks = K + hb + (size_t)(kb + (g >> 2) * 16 + l15) * DIM + (g & 3) * 32 + q4 * 8;
            kr[p][0] = *(const float4*)ks;
            kr[p][1] = *(const float4*)(ks + 4);
            const float* vs = V + hb + (size_t)(kb + (g & 1) * 32 + q4 * 8) * DIM + (g >> 1) * 16 + l15;
            #pragma unroll
            for (int j = 0; j < 8; ++j) vr[p][j] = vs[j * DIM];
        }
    };
    auto commit = [&](int buf) {
        #pragma unroll
        for (int p = 0; p < 4; ++p) {
            const int g = p * 4 + w;
            union { short8 s; uint32_t u[4]; } uk, uv;
            uk.u[0] = pack_bf16x2(kr[p][0].x, kr[p][0].y);
            uk.u[1] = pack_bf16x2(kr[p][0].z, kr[p][0].w);
            uk.u[2] = pack_bf16x2(kr[p][1].x, kr[p][1].y);
            uk.u[3] = pack_bf16x2(kr[p][1].z, kr[p][1].w);
            *(short8*)(&kblob[buf][(g * 64 + lane) * 8]) = uk.s;
            uv.u[0] = pack_bf16x2(vr[p][0], vr[p][1]);
            uv.u[1] = pack_bf16x2(vr[p][2], vr[p][3]);
            uv.u[2] = pack_bf16x2(vr[p][4], vr[p][5]);
            uv.u[3] = pack_bf16x2(vr[p][6], vr[p][7]);
            *(short8*)(&vblob[buf][(g * 64 + lane) * 8]) = uv.s;
        }
    };

    issue(0);
    commit(0);
    __syncthreads();

    const int kend = qb + QROWS;
    int buf = 0;
    for (int kb = 0; kb < kend; kb += BK) {
        const bool more = (kb + BK) < kend;
        if (more) issue(kb + BK);               // prefetch next tile (hidden under compute)

        const bool act0 = kb <= row0[0] + 15;   // h=1 is always active for executed kb

        // ---- QK^T: 4 col-chunks x k=128 (4 chained MFMAs); K-frags shared across h
        floatx4 sc[2][4];
        #pragma unroll
        for (int h = 0; h < 2; ++h)
            #pragma unroll
            for (int c = 0; c < 4; ++c) sc[h][c] = (floatx4){0.f,0.f,0.f,0.f};
        #pragma unroll
        for (int kk = 0; kk < 4; ++kk) {
            #pragma unroll
            for (int c = 0; c < 4; ++c) {
                short8 b = *(const short8*)(&kblob[buf][((c * 4 + kk) * 64 + lane) * 8]);
                if (act0) sc[0][c] = __builtin_amdgcn_mfma_f32_16x16x32_bf16(qf[0][kk], b, sc[0][c], 0, 0, 0);
                sc[1][c] = __builtin_amdgcn_mfma_f32_16x16x32_bf16(qf[1][kk], b, sc[1][c], 0, 0, 0);
            }
        }

        // ---- online softmax (base-2) + P-blob write per h
        #pragma unroll
        for (int h = 0; h < 2; ++h) {
            if (h == 0 && !act0) continue;
            float mx[4];
            #pragma unroll
            for (int r = 0; r < 4; ++r) {
                const int rg = row0[h] + q4 * 4 + r;
                float m = -1e38f;
                #pragma unroll
                for (int c = 0; c < 4; ++c) {
                    float a = sc[h][c][r] * QK_SCALE_LOG2E;
                    a = (kb + c * 16 + l15 <= rg) ? a : -1e38f;
                    sc[h][c][r] = a;
                    m = fmaxf(m, a);
                }
                mx[r] = m;
            }
            #pragma unroll
            for (int r = 0; r < 4; ++r) {
                float v = mx[r];
                v = fmaxf(v, __shfl_xor(v, 1));
                v = fmaxf(v, __shfl_xor(v, 2));
                v = fmaxf(v, __shfl_xor(v, 4));
                v = fmaxf(v, __shfl_xor(v, 8));
                mx[r] = v;
            }
            float alpha[4], rsum[4];
            #pragma unroll
            for (int r = 0; r < 4; ++r) {
                const float mnew = fmaxf(m_i[h][r], mx[r]);
                alpha[r] = __builtin_amdgcn_exp2f(m_i[h][r] - mnew);
                m_i[h][r] = mnew;
                float s = 0.f;
                #pragma unroll
                for (int c = 0; c < 4; ++c) {
                    const float p = __builtin_amdgcn_exp2f(sc[h][c][r] - mnew);
                    sc[h][c][r] = p;
                    s += p;
                }
                rsum[r] = s;
            }
            #pragma unroll
            for (int r = 0; r < 4; ++r) {
                float v = rsum[r];
                v += __shfl_xor(v, 1);
                v += __shfl_xor(v, 2);
                v += __shfl_xor(v, 4);
                v += __shfl_xor(v, 8);
                l_i[h][r] = l_i[h][r] * alpha[r] + v;
            }
            // P: C-layout -> A-fragment blob
            #pragma unroll
            for (int c = 0; c < 4; ++c) {
                ushort* pw = pblob[w][h][c >> 1];
                const int wo = ((c & 1) * 2 + (l15 >> 3)) * 16;
                #pragma unroll
                for (int r = 0; r < 4; ++r)
                    pw[(wo + q4 * 4 + r) * 8 + (l15 & 7)] = f2bf_rn(sc[h][c][r]);
            }
            #pragma unroll
            for (int t = 0; t < 8; ++t)
                #pragma unroll
                for (int r = 0; r < 4; ++r)
                    o_acc[h][t][r] *= alpha[r];
        }
        asm volatile("s_waitcnt lgkmcnt(0)" ::: "memory"); // wave-local RAW on pblob
        short8 pf[2][2];
        if (act0) {
            pf[0][0] = *(const short8*)(&pblob[w][0][0][lane * 8]);
            pf[0][1] = *(const short8*)(&pblob[w][0][1][lane * 8]);
        }
        pf[1][0] = *(const short8*)(&pblob[w][1][0][lane * 8]);
        pf[1][1] = *(const short8*)(&pblob[w][1][1][lane * 8]);

        // ---- PV: V-frags shared across h
        #pragma unroll
        for (int t = 0; t < 8; ++t) {
            #pragma unroll
            for (int kc = 0; kc < 2; ++kc) {
                short8 vf = *(const short8*)(&vblob[buf][((t * 2 + kc) * 64 + lane) * 8]);
                if (act0) o_acc[0][t] = __builtin_amdgcn_mfma_f32_16x16x32_bf16(pf[0][kc], vf, o_acc[0][t], 0, 0, 0);
                o_acc[1][t] = __builtin_amdgcn_mfma_f32_16x16x32_bf16(pf[1][kc], vf, o_acc[1][t], 0, 0, 0);
            }
        }

        if (more) commit(buf ^ 1);              // write prefetched tile to alternate buffer
        __syncthreads();
        buf ^= 1;
    }

    // ---- epilogue: O = acc / l_i
    #pragma unroll
    for (int h = 0; h < 2; ++h) {
        float inv[4];
        #pragma unroll
        for (int r = 0; r < 4; ++r) inv[r] = __builtin_amdgcn_rcpf(l_i[h][r]);
        #pragma unroll
        for (int t = 0; t < 8; ++t) {
            #pragma unroll
            for (int r = 0; r < 4; ++r) {
                const int rg = row0[h] + q4 * 4 + r;
                O[hb + (size_t)rg * DIM + t * 16 + l15] = o_acc[h][t][r] * inv[r];
            }
        }
    }
}

extern "C" void kernel_launch(void* const* d_in, const int* in_sizes, int n_in,
                              void* d_out, int out_size, void* d_ws, size_t ws_size,
                              hipStream_t stream) {
    const float* q = (const float*)d_in[0];
    const float* k = (const float*)d_in[1];
    const float* v = (const float*)d_in[2];
    float* o = (float*)d_out;
    dim3 grid(SEQ / QROWS, BATCH * HEADS);
    fa_fwd<<<grid, dim3(256), 0, stream>>>(q, k, v, o);
}

// Round 5
// 518.139 us; speedup vs baseline: 1.8441x; 1.1604x over previous
//
#include <hip/hip_runtime.h>
#include <stdint.h>

#define BATCH 4
#define HEADS 16
#define SEQ   2048
#define DIM   128
#define QROWS 128   // per block: 4 waves, each owns rows qb+16w (h=0) and qb+64+16w (h=1)
#define BK    64

typedef short short8 __attribute__((ext_vector_type(8)));
typedef float floatx4 __attribute__((ext_vector_type(4)));

// 1/sqrt(128) * log2(e): softmax in base-2 domain
#define QK_SCALE_LOG2E 0.1274750709470246f

static __device__ __forceinline__ ushort f2bf_rn(float f) {
    union { float f; uint32_t u; } x; x.f = f;
    return (ushort)((x.u + 0x8000u) >> 16);
}
static __device__ __forceinline__ uint32_t pack_bf16x2(float f0, float f1) {
    union { float f; uint32_t u; } a, b; a.f = f0; b.f = f1;
    return __builtin_amdgcn_perm(b.u + 0x8000u, a.u + 0x8000u, 0x07060302u);
}

__global__ __launch_bounds__(256, 2)
void fa_fwd(const float* __restrict__ Q, const float* __restrict__ K,
            const float* __restrict__ V, float* __restrict__ O)
{
    const int qt = gridDim.x - 1 - blockIdx.x;   // heavy q-tiles first
    const int qb = qt * QROWS;
    const size_t hb = (size_t)blockIdx.y * SEQ * DIM;

    const int tid  = threadIdx.x;
    const int w    = tid >> 6;
    const int lane = tid & 63;
    const int l15  = lane & 15;
    const int q4   = lane >> 4;

    // Fragment-order blobs, double-buffered. Every access is b128 at lane*16B.
    // kblob group g=c*4+kk: elem = K[kb+c*16+l15][kk*32+q4*8+j]
    // vblob group g=t*2+kc: elem = V[kb+kc*32+q4*8+j][t*16+l15]
    __shared__ ushort kblob[2][16 * 64 * 8];    // 32 KB
    __shared__ ushort vblob[2][16 * 64 * 8];    // 32 KB
    __shared__ ushort pblob[4][2][64 * 8];      // 8 KB: [wave][kc], shared across h

    const int row0[2] = { qb + w * 16, qb + 64 + w * 16 };

    // ---- Q fragments (A-layout), f32->bf16, persistent in registers
    short8 qf[2][4];
    #pragma unroll
    for (int h = 0; h < 2; ++h) {
        const float* qp = Q + hb + (size_t)(row0[h] + l15) * DIM + q4 * 8;
        #pragma unroll
        for (int kk = 0; kk < 4; ++kk) {
            float4 a = *(const float4*)(qp + kk * 32);
            float4 b = *(const float4*)(qp + kk * 32 + 4);
            union { short8 s; uint32_t u[4]; } u_;
            u_.u[0] = pack_bf16x2(a.x, a.y);
            u_.u[1] = pack_bf16x2(a.z, a.w);
            u_.u[2] = pack_bf16x2(b.x, b.y);
            u_.u[3] = pack_bf16x2(b.z, b.w);
            qf[h][kk] = u_.s;
        }
    }

    floatx4 o_acc[2][8];
    float m_i[2][4], l_i[2][4];
    #pragma unroll
    for (int h = 0; h < 2; ++h) {
        #pragma unroll
        for (int t = 0; t < 8; ++t) o_acc[h][t] = (floatx4){0.f, 0.f, 0.f, 0.f};
        #pragma unroll
        for (int r = 0; r < 4; ++r) { m_i[h][r] = -1e38f; l_i[h][r] = 0.f; }
    }

    // ---- two-phase staging: K regs live only through QK, V regs only through PV
    float4 kr[4][2];
    float  vr[4][8];

    auto issue_k = [&](int kb) {
        #pragma unroll
        for (int p = 0; p < 4; ++p) {
            const int g = p * 4 + w;
            const float* ks = K + hb + (size_t)(kb + (g >> 2) * 16 + l15) * DIM + (g & 3) * 32 + q4 * 8;
            kr[p][0] = *(const float4*)ks;
            kr[p][1] = *(const float4*)(ks + 4);
        }
    };
    auto commit_k = [&](int buf) {
        #pragma unroll
        for (int p = 0; p < 4; ++p) {
            const int g = p * 4 + w;
            union { short8 s; uint32_t u[4]; } u_;
            u_.u[0] = pack_bf16x2(kr[p][0].x, kr[p][0].y);
            u_.u[1] = pack_bf16x2(kr[p][0].z, kr[p][0].w);
            u_.u[2] = pack_bf16x2(kr[p][1].x, kr[p][1].y);
            u_.u[3] = pack_bf16x2(kr[p][1].z, kr[p][1].w);
            *(short8*)(&kblob[buf][(g * 64 + lane) * 8]) = u_.s;
        }
    };
    auto issue_v = [&](int kb) {
        #pragma unroll
        for (int p = 0; p < 4; ++p) {
            const int g = p * 4 + w;
            const float* vs = V + hb + (size_t)(kb + (g & 1) * 32 + q4 * 8) * DIM + (g >> 1) * 16 + l15;
            #pragma unroll
            for (int j = 0; j < 8; ++j) vr[p][j] = vs[j * DIM];
        }
    };
    auto commit_v = [&](int buf) {
        #pragma unroll
        for (int p = 0; p < 4; ++p) {
            const int g = p * 4 + w;
            union { short8 s; uint32_t u[4]; } u_;
            u_.u[0] = pack_bf16x2(vr[p][0], vr[p][1]);
            u_.u[1] = pack_bf16x2(vr[p][2], vr[p][3]);
            u_.u[2] = pack_bf16x2(vr[p][4], vr[p][5]);
            u_.u[3] = pack_bf16x2(vr[p][6], vr[p][7]);
            *(short8*)(&vblob[buf][(g * 64 + lane) * 8]) = u_.s;
        }
    };

    issue_k(0); commit_k(0);
    issue_v(0); commit_v(0);
    __syncthreads();

    const int kend = qb + QROWS;
    int buf = 0;
    for (int kb = 0; kb < kend; kb += BK) {
        const bool more = (kb + BK) < kend;
        if (more) issue_k(kb + BK);             // K prefetch in flight during QK

        const bool act0 = kb <= row0[0] + 15;   // h=1 always active for executed kb

        // ---- QK^T: 4 col-chunks x k=128; K-frags shared across h
        floatx4 sc[2][4];
        #pragma unroll
        for (int h = 0; h < 2; ++h)
            #pragma unroll
            for (int c = 0; c < 4; ++c) sc[h][c] = (floatx4){0.f,0.f,0.f,0.f};
        #pragma unroll
        for (int kk = 0; kk < 4; ++kk) {
            #pragma unroll
            for (int c = 0; c < 4; ++c) {
                short8 b = *(const short8*)(&kblob[buf][((c * 4 + kk) * 64 + lane) * 8]);
                if (act0) sc[0][c] = __builtin_amdgcn_mfma_f32_16x16x32_bf16(qf[0][kk], b, sc[0][c], 0, 0, 0);
                sc[1][c] = __builtin_amdgcn_mfma_f32_16x16x32_bf16(qf[1][kk], b, sc[1][c], 0, 0, 0);
            }
        }

        if (more) { commit_k(buf ^ 1); issue_v(kb + BK); }  // V prefetch during softmax+PV

        // ---- online softmax (base-2) + P A-frag build, h sequential (shared pblob)
        short8 pf[2][2];
        #pragma unroll
        for (int h = 0; h < 2; ++h) {
            if (h == 0 && !act0) continue;
            float mx[4];
            #pragma unroll
            for (int r = 0; r < 4; ++r) {
                const int rg = row0[h] + q4 * 4 + r;
                float m = -1e38f;
                #pragma unroll
                for (int c = 0; c < 4; ++c) {
                    float a = sc[h][c][r] * QK_SCALE_LOG2E;
                    a = (kb + c * 16 + l15 <= rg) ? a : -1e38f;
                    sc[h][c][r] = a;
                    m = fmaxf(m, a);
                }
                mx[r] = m;
            }
            #pragma unroll
            for (int r = 0; r < 4; ++r) {
                float v = mx[r];
                v = fmaxf(v, __shfl_xor(v, 1));
                v = fmaxf(v, __shfl_xor(v, 2));
                v = fmaxf(v, __shfl_xor(v, 4));
                v = fmaxf(v, __shfl_xor(v, 8));
                mx[r] = v;
            }
            float alpha[4], rsum[4];
            #pragma unroll
            for (int r = 0; r < 4; ++r) {
                const float mnew = fmaxf(m_i[h][r], mx[r]);
                alpha[r] = __builtin_amdgcn_exp2f(m_i[h][r] - mnew);
                m_i[h][r] = mnew;
                float s = 0.f;
                #pragma unroll
                for (int c = 0; c < 4; ++c) {
                    const float p = __builtin_amdgcn_exp2f(sc[h][c][r] - mnew);
                    sc[h][c][r] = p;
                    s += p;
                }
                rsum[r] = s;
            }
            #pragma unroll
            for (int r = 0; r < 4; ++r) {
                float v = rsum[r];
                v += __shfl_xor(v, 1);
                v += __shfl_xor(v, 2);
                v += __shfl_xor(v, 4);
                v += __shfl_xor(v, 8);
                l_i[h][r] = l_i[h][r] * alpha[r] + v;
            }
            // P: C-layout -> A-fragment blob (shared buffer, wave-local ordering)
            #pragma unroll
            for (int c = 0; c < 4; ++c) {
                ushort* pw = pblob[w][c >> 1];
                const int wo = ((c & 1) * 2 + (l15 >> 3)) * 16;
                #pragma unroll
                for (int r = 0; r < 4; ++r)
                    pw[(wo + q4 * 4 + r) * 8 + (l15 & 7)] = f2bf_rn(sc[h][c][r]);
            }
            asm volatile("s_waitcnt lgkmcnt(0)" ::: "memory");
            pf[h][0] = *(const short8*)(&pblob[w][0][lane * 8]);
            pf[h][1] = *(const short8*)(&pblob[w][1][lane * 8]);
            #pragma unroll
            for (int t = 0; t < 8; ++t)
                #pragma unroll
                for (int r = 0; r < 4; ++r)
                    o_acc[h][t][r] *= alpha[r];
        }

        // ---- PV: V-frags shared across h
        #pragma unroll
        for (int t = 0; t < 8; ++t) {
            #pragma unroll
            for (int kc = 0; kc < 2; ++kc) {
                short8 vf = *(const short8*)(&vblob[buf][((t * 2 + kc) * 64 + lane) * 8]);
                if (act0) o_acc[0][t] = __builtin_amdgcn_mfma_f32_16x16x32_bf16(pf[0][kc], vf, o_acc[0][t], 0, 0, 0);
                o_acc[1][t] = __builtin_amdgcn_mfma_f32_16x16x32_bf16(pf[1][kc], vf, o_acc[1][t], 0, 0, 0);
            }
        }

        if (more) commit_v(buf ^ 1);
        __syncthreads();
        buf ^= 1;
    }

    // ---- epilogue: O = acc / l_i
    #pragma unroll
    for (int h = 0; h < 2; ++h) {
        float inv[4];
        #pragma unroll
        for (int r = 0; r < 4; ++r) inv[r] = __builtin_amdgcn_rcpf(l_i[h][r]);
        #pragma unroll
        for (int t = 0; t < 8; ++t) {
            #pragma unroll
            for (int r = 0; r < 4; ++r) {
                const int rg = row0[h] + q4 * 4 + r;
                O[hb + (size_t)rg * DIM + t * 16 + l15] = o_acc[h][t][r] * inv[r];
            }
        }
    }
}

extern "C" void kernel_launch(void* const* d_in, const int* in_sizes, int n_in,
                              void* d_out, int out_size, void* d_ws, size_t ws_size,
                              hipStream_t stream) {
    const float* q = (const float*)d_in[0];
    const float* k = (const float*)d_in[1];
    const float* v = (const float*)d_in[2];
    float* o = (float*)d_out;
    dim3 grid(SEQ / QROWS, BATCH * HEADS);
    fa_fwd<<<grid, dim3(256), 0, stream>>>(q, k, v, o);
}

// Round 6
// 496.127 us; speedup vs baseline: 1.9259x; 1.0444x over previous
//
#include <hip/hip_runtime.h>
#include <stdint.h>

#define BATCH 4
#define HEADS 16
#define SEQ   2048
#define DIM   128
#define QROWS 128   // per block: 4 waves, each owns rows qb+16w (h=0) and qb+64+16w (h=1)
#define BK    64
#define KT_TILES (SEQ / BK)   // 32

typedef short short8 __attribute__((ext_vector_type(8)));
typedef float floatx4 __attribute__((ext_vector_type(4)));

// 1/sqrt(128) * log2(e): softmax in base-2 domain
#define QK_SCALE_LOG2E 0.1274750709470246f

static __device__ __forceinline__ ushort f2bf_rn(float f) {
    union { float f; uint32_t u; } x; x.f = f;
    return (ushort)((x.u + 0x8000u) >> 16);
}
static __device__ __forceinline__ uint32_t pack_bf16x2(float f0, float f1) {
    union { float f; uint32_t u; } a, b; a.f = f0; b.f = f1;
    return __builtin_amdgcn_perm(b.u + 0x8000u, a.u + 0x8000u, 0x07060302u);
}

#define GLOAD_LDS16(gsrc, ldst) \
    __builtin_amdgcn_global_load_lds( \
        (const __attribute__((address_space(1))) uint32_t*)(gsrc), \
        (__attribute__((address_space(3))) uint32_t*)(ldst), 16, 0, 0)

// ============================================================================
// Pass 1: convert Q -> bf16 row-major; K,V -> bf16 MFMA-fragment blobs.
// Blob unit per (bh, kt): 16 groups x 64 lanes x 8 ush = 16 KB.
//   K group g=c*4+kk, lane, j:  K[kt*64 + c*16 + l15][kk*32 + q4*8 + j]
//   V group g=t*2+kc, lane, j:  V[kt*64 + kc*32 + q4*8 + j][t*16 + l15]
// ============================================================================
__global__ __launch_bounds__(256)
void convert_qkv(const float* __restrict__ Q, const float* __restrict__ K,
                 const float* __restrict__ V, ushort* __restrict__ Qb,
                 ushort* __restrict__ Kb, ushort* __restrict__ Vb)
{
    const int bid = blockIdx.x;
    if (bid < 8192) {
        // ---- Q: 2048 elems per block, 8 per thread
        const size_t base = (size_t)bid * 2048 + threadIdx.x * 8;
        float4 a = *(const float4*)(Q + base);
        float4 b = *(const float4*)(Q + base + 4);
        union { short8 s; uint32_t u[4]; } u_;
        u_.u[0] = pack_bf16x2(a.x, a.y);
        u_.u[1] = pack_bf16x2(a.z, a.w);
        u_.u[2] = pack_bf16x2(b.x, b.y);
        u_.u[3] = pack_bf16x2(b.z, b.w);
        *(short8*)(Qb + base) = u_.s;
    } else if (bid < 16384) {
        // ---- K blob: one wave per (bh, kt, g)
        const int wid  = (bid - 8192) * 4 + (threadIdx.x >> 6);
        const int lane = threadIdx.x & 63;
        const int l15  = lane & 15, q4 = lane >> 4;
        const int bh = wid >> 9, kt = (wid >> 4) & 31, g = wid & 15;
        const int row = kt * 64 + (g >> 2) * 16 + l15;
        const int col = (g & 3) * 32 + q4 * 8;
        const float* s = K + ((size_t)bh * SEQ + row) * DIM + col;
        float4 a = *(const float4*)s;
        float4 b = *(const float4*)(s + 4);
        union { short8 sv; uint32_t u[4]; } u_;
        u_.u[0] = pack_bf16x2(a.x, a.y);
        u_.u[1] = pack_bf16x2(a.z, a.w);
        u_.u[2] = pack_bf16x2(b.x, b.y);
        u_.u[3] = pack_bf16x2(b.z, b.w);
        *(short8*)(Kb + ((size_t)(bh * KT_TILES + kt) * 16 + g) * 512 + lane * 8) = u_.sv;
    } else {
        // ---- V blob (transposed gather): one wave per (bh, kt, g)
        const int wid  = (bid - 16384) * 4 + (threadIdx.x >> 6);
        const int lane = threadIdx.x & 63;
        const int l15  = lane & 15, q4 = lane >> 4;
        const int bh = wid >> 9, kt = (wid >> 4) & 31, g = wid & 15;
        const int row = kt * 64 + (g & 1) * 32 + q4 * 8;
        const int col = (g >> 1) * 16 + l15;
        const float* s = V + ((size_t)bh * SEQ + row) * DIM + col;
        float v0 = s[0 * DIM], v1 = s[1 * DIM], v2 = s[2 * DIM], v3 = s[3 * DIM];
        float v4 = s[4 * DIM], v5 = s[5 * DIM], v6 = s[6 * DIM], v7 = s[7 * DIM];
        union { short8 sv; uint32_t u[4]; } u_;
        u_.u[0] = pack_bf16x2(v0, v1);
        u_.u[1] = pack_bf16x2(v2, v3);
        u_.u[2] = pack_bf16x2(v4, v5);
        u_.u[3] = pack_bf16x2(v6, v7);
        *(short8*)(Vb + ((size_t)(bh * KT_TILES + kt) * 16 + g) * 512 + lane * 8) = u_.sv;
    }
}

// ============================================================================
// Pass 2: flash attention, all-bf16 inputs, async global->LDS staging.
// ============================================================================
__global__ __launch_bounds__(256, 2)
void fa_fwd(const ushort* __restrict__ Qb, const ushort* __restrict__ Kb,
            const ushort* __restrict__ Vb, float* __restrict__ O)
{
    const int qt = gridDim.x - 1 - blockIdx.x;   // heavy q-tiles first
    const int qb = qt * QROWS;
    const int bh = blockIdx.y;
    const size_t hb = (size_t)bh * SEQ * DIM;

    const int tid  = threadIdx.x;
    const int w    = tid >> 6;
    const int lane = tid & 63;
    const int l15  = lane & 15;
    const int q4   = lane >> 4;

    __shared__ ushort kblob[2][16 * 64 * 8];    // 32 KB
    __shared__ ushort vblob[2][16 * 64 * 8];    // 32 KB
    __shared__ ushort pblob[4][2][64 * 8];      // 8 KB: [wave][kc], shared across h

    const int row0[2] = { qb + w * 16, qb + 64 + w * 16 };

    // ---- Q fragments (A-layout) straight from bf16 global
    short8 qf[2][4];
    #pragma unroll
    for (int h = 0; h < 2; ++h) {
        const ushort* qp = Qb + hb + (size_t)(row0[h] + l15) * DIM + q4 * 8;
        #pragma unroll
        for (int kk = 0; kk < 4; ++kk)
            qf[h][kk] = *(const short8*)(qp + kk * 32);
    }

    floatx4 o_acc[2][8];
    float m_i[2][4], l_i[2][4];
    #pragma unroll
    for (int h = 0; h < 2; ++h) {
        #pragma unroll
        for (int t = 0; t < 8; ++t) o_acc[h][t] = (floatx4){0.f, 0.f, 0.f, 0.f};
        #pragma unroll
        for (int r = 0; r < 4; ++r) { m_i[h][r] = -1e38f; l_i[h][r] = 0.f; }
    }

    // ---- async DMA staging: no VGPRs, no conversion
    auto stage = [&](int kt, int buf) {
        const size_t tb = ((size_t)(bh * KT_TILES + kt)) * (16 * 512);
        #pragma unroll
        for (int p = 0; p < 4; ++p) {
            const int g = p * 4 + w;
            GLOAD_LDS16(Kb + tb + g * 512 + lane * 8, &kblob[buf][g * 512]);
            GLOAD_LDS16(Vb + tb + g * 512 + lane * 8, &vblob[buf][g * 512]);
        }
    };

    stage(0, 0);
    __syncthreads();

    const int ktend = (qb + QROWS) / BK;
    int buf = 0;
    for (int kt = 0; kt < ktend; ++kt) {
        const int kb = kt * BK;
        const bool more = (kt + 1) < ktend;
        if (more) stage(kt + 1, buf ^ 1);       // DMA hidden under compute

        const bool act0 = kb <= row0[0] + 15;   // h=1 always active for executed kb

        // ---- QK^T: 4 col-chunks x k=128; K-frags shared across h
        floatx4 sc[2][4];
        #pragma unroll
        for (int h = 0; h < 2; ++h)
            #pragma unroll
            for (int c = 0; c < 4; ++c) sc[h][c] = (floatx4){0.f,0.f,0.f,0.f};
        #pragma unroll
        for (int kk = 0; kk < 4; ++kk) {
            #pragma unroll
            for (int c = 0; c < 4; ++c) {
                short8 b = *(const short8*)(&kblob[buf][((c * 4 + kk) * 64 + lane) * 8]);
                if (act0) sc[0][c] = __builtin_amdgcn_mfma_f32_16x16x32_bf16(qf[0][kk], b, sc[0][c], 0, 0, 0);
                sc[1][c] = __builtin_amdgcn_mfma_f32_16x16x32_bf16(qf[1][kk], b, sc[1][c], 0, 0, 0);
            }
        }

        // ---- online softmax (base-2) + P A-frag build, h sequential (shared pblob)
        short8 pf[2][2];
        #pragma unroll
        for (int h = 0; h < 2; ++h) {
            if (h == 0 && !act0) continue;
            float mx[4];
            #pragma unroll
            for (int r = 0; r < 4; ++r) {
                const int rg = row0[h] + q4 * 4 + r;
                float m = -1e38f;
                #pragma unroll
                for (int c = 0; c < 4; ++c) {
                    float a = sc[h][c][r] * QK_SCALE_LOG2E;
                    a = (kb + c * 16 + l15 <= rg) ? a : -1e38f;
                    sc[h][c][r] = a;
                    m = fmaxf(m, a);
                }
                mx[r] = m;
            }
            #pragma unroll
            for (int r = 0; r < 4; ++r) {
                float v = mx[r];
                v = fmaxf(v, __shfl_xor(v, 1));
                v = fmaxf(v, __shfl_xor(v, 2));
                v = fmaxf(v, __shfl_xor(v, 4));
                v = fmaxf(v, __shfl_xor(v, 8));
                mx[r] = v;
            }
            float alpha[4], rsum[4];
            #pragma unroll
            for (int r = 0; r < 4; ++r) {
                const float mnew = fmaxf(m_i[h][r], mx[r]);
                alpha[r] = __builtin_amdgcn_exp2f(m_i[h][r] - mnew);
                m_i[h][r] = mnew;
                float s = 0.f;
                #pragma unroll
                for (int c = 0; c < 4; ++c) {
                    const float p = __builtin_amdgcn_exp2f(sc[h][c][r] - mnew);
                    sc[h][c][r] = p;
                    s += p;
                }
                rsum[r] = s;
            }
            #pragma unroll
            for (int r = 0; r < 4; ++r) {
                float v = rsum[r];
                v += __shfl_xor(v, 1);
                v += __shfl_xor(v, 2);
                v += __shfl_xor(v, 4);
                v += __shfl_xor(v, 8);
                l_i[h][r] = l_i[h][r] * alpha[r] + v;
            }
            #pragma unroll
            for (int c = 0; c < 4; ++c) {
                ushort* pw = pblob[w][c >> 1];
                const int wo = ((c & 1) * 2 + (l15 >> 3)) * 16;
                #pragma unroll
                for (int r = 0; r < 4; ++r)
                    pw[(wo + q4 * 4 + r) * 8 + (l15 & 7)] = f2bf_rn(sc[h][c][r]);
            }
            asm volatile("s_waitcnt lgkmcnt(0)" ::: "memory");
            pf[h][0] = *(const short8*)(&pblob[w][0][lane * 8]);
            pf[h][1] = *(const short8*)(&pblob[w][1][lane * 8]);
            #pragma unroll
            for (int t = 0; t < 8; ++t)
                #pragma unroll
                for (int r = 0; r < 4; ++r)
                    o_acc[h][t][r] *= alpha[r];
        }

        // ---- PV: V-frags shared across h
        #pragma unroll
        for (int t = 0; t < 8; ++t) {
            #pragma unroll
            for (int kc = 0; kc < 2; ++kc) {
                short8 vf = *(const short8*)(&vblob[buf][((t * 2 + kc) * 64 + lane) * 8]);
                if (act0) o_acc[0][t] = __builtin_amdgcn_mfma_f32_16x16x32_bf16(pf[0][kc], vf, o_acc[0][t], 0, 0, 0);
                o_acc[1][t] = __builtin_amdgcn_mfma_f32_16x16x32_bf16(pf[1][kc], vf, o_acc[1][t], 0, 0, 0);
            }
        }

        __syncthreads();   // drains DMA vmcnt + all LDS reads before buffer swap
        buf ^= 1;
    }

    // ---- epilogue: O = acc / l_i
    #pragma unroll
    for (int h = 0; h < 2; ++h) {
        float inv[4];
        #pragma unroll
        for (int r = 0; r < 4; ++r) inv[r] = __builtin_amdgcn_rcpf(l_i[h][r]);
        #pragma unroll
        for (int t = 0; t < 8; ++t) {
            #pragma unroll
            for (int r = 0; r < 4; ++r) {
                const int rg = row0[h] + q4 * 4 + r;
                O[hb + (size_t)rg * DIM + t * 16 + l15] = o_acc[h][t][r] * inv[r];
            }
        }
    }
}

// ============================================================================
// Fallback (R5 kernel): used only if ws_size < 96 MB.
// ============================================================================
__global__ __launch_bounds__(256, 2)
void fa_fwd_fb(const float* __restrict__ Q, const float* __restrict__ K,
               const float* __restrict__ V, float* __restrict__ O)
{
    const int qt = gridDim.x - 1 - blockIdx.x;
    const int qb = qt * QROWS;
    const size_t hb = (size_t)blockIdx.y * SEQ * DIM;
    const int tid  = threadIdx.x;
    const int w    = tid >> 6;
    const int lane = tid & 63;
    const int l15  = lane & 15;
    const int q4   = lane >> 4;

    __shared__ ushort kblob[2][16 * 64 * 8];
    __shared__ ushort vblob[2][16 * 64 * 8];
    __shared__ ushort pblob[4][2][64 * 8];

    const int row0[2] = { qb + w * 16, qb + 64 + w * 16 };
    short8 qf[2][4];
    #pragma unroll
    for (int h = 0; h < 2; ++h) {
        const float* qp = Q + hb + (size_t)(row0[h] + l15) * DIM + q4 * 8;
        #pragma unroll
        for (int kk = 0; kk < 4; ++kk) {
            float4 a = *(const float4*)(qp + kk * 32);
            float4 b = *(const float4*)(qp + kk * 32 + 4);
            union { short8 s; uint32_t u[4]; } u_;
            u_.u[0] = pack_bf16x2(a.x, a.y);
            u_.u[1] = pack_bf16x2(a.z, a.w);
            u_.u[2] = pack_bf16x2(b.x, b.y);
            u_.u[3] = pack_bf16x2(b.z, b.w);
            qf[h][kk] = u_.s;
        }
    }
    floatx4 o_acc[2][8];
    float m_i[2][4], l_i[2][4];
    #pragma unroll
    for (int h = 0; h < 2; ++h) {
        #pragma unroll
        for (int t = 0; t < 8; ++t) o_acc[h][t] = (floatx4){0.f, 0.f, 0.f, 0.f};
        #pragma unroll
        for (int r = 0; r < 4; ++r) { m_i[h][r] = -1e38f; l_i[h][r] = 0.f; }
    }
    float4 kr[4][2];
    float  vr[4][8];
    auto issue_k = [&](int kb) {
        #pragma unroll
        for (int p = 0; p < 4; ++p) {
            const int g = p * 4 + w;
            const float* ks = K + hb + (size_t)(kb + (g >> 2) * 16 + l15) * DIM + (g & 3) * 32 + q4 * 8;
            kr[p][0] = *(const float4*)ks;
            kr[p][1] = *(const float4*)(ks + 4);
        }
    };
    auto commit_k = [&](int buf) {
        #pragma unroll
        for (int p = 0; p < 4; ++p) {
            const int g = p * 4 + w;
            union { short8 s; uint32_t u[4]; } u_;
            u_.u[0] = pack_bf16x2(kr[p][0].x, kr[p][0].y);
            u_.u[1] = pack_bf16x2(kr[p][0].z, kr[p][0].w);
            u_.u[2] = pack_bf16x2(kr[p][1].x, kr[p][1].y);
            u_.u[3] = pack_bf16x2(kr[p][1].z, kr[p][1].w);
            *(short8*)(&kblob[buf][(g * 64 + lane) * 8]) = u_.s;
        }
    };
    auto issue_v = [&](int kb) {
        #pragma unroll
        for (int p = 0; p < 4; ++p) {
            const int g = p * 4 + w;
            const float* vs = V + hb + (size_t)(kb + (g & 1) * 32 + q4 * 8) * DIM + (g >> 1) * 16 + l15;
            #pragma unroll
            for (int j = 0; j < 8; ++j) vr[p][j] = vs[j * DIM];
        }
    };
    auto commit_v = [&](int buf) {
        #pragma unroll
        for (int p = 0; p < 4; ++p) {
            const int g = p * 4 + w;
            union { short8 s; uint32_t u[4]; } u_;
            u_.u[0] = pack_bf16x2(vr[p][0], vr[p][1]);
            u_.u[1] = pack_bf16x2(vr[p][2], vr[p][3]);
            u_.u[2] = pack_bf16x2(vr[p][4], vr[p][5]);
            u_.u[3] = pack_bf16x2(vr[p][6], vr[p][7]);
            *(short8*)(&vblob[buf][(g * 64 + lane) * 8]) = u_.s;
        }
    };
    issue_k(0); commit_k(0);
    issue_v(0); commit_v(0);
    __syncthreads();
    const int kend = qb + QROWS;
    int buf = 0;
    for (int kb = 0; kb < kend; kb += BK) {
        const bool more = (kb + BK) < kend;
        if (more) issue_k(kb + BK);
        const bool act0 = kb <= row0[0] + 15;
        floatx4 sc[2][4];
        #pragma unroll
        for (int h = 0; h < 2; ++h)
            #pragma unroll
            for (int c = 0; c < 4; ++c) sc[h][c] = (floatx4){0.f,0.f,0.f,0.f};
        #pragma unroll
        for (int kk = 0; kk < 4; ++kk) {
            #pragma unroll
            for (int c = 0; c < 4; ++c) {
                short8 b = *(const short8*)(&kblob[buf][((c * 4 + kk) * 64 + lane) * 8]);
                if (act0) sc[0][c] = __builtin_amdgcn_mfma_f32_16x16x32_bf16(qf[0][kk], b, sc[0][c], 0, 0, 0);
                sc[1][c] = __builtin_amdgcn_mfma_f32_16x16x32_bf16(qf[1][kk], b, sc[1][c], 0, 0, 0);
            }
        }
        if (more) { commit_k(buf ^ 1); issue_v(kb + BK); }
        short8 pf[2][2];
        #pragma unroll
        for (int h = 0; h < 2; ++h) {
            if (h == 0 && !act0) continue;
            float mx[4];
            #pragma unroll
            for (int r = 0; r < 4; ++r) {
                const int rg = row0[h] + q4 * 4 + r;
                float m = -1e38f;
                #pragma unroll
                for (int c = 0; c < 4; ++c) {
                    float a = sc[h][c][r] * QK_SCALE_LOG2E;
                    a = (kb + c * 16 + l15 <= rg) ? a : -1e38f;
                    sc[h][c][r] = a;
                    m = fmaxf(m, a);
                }
                mx[r] = m;
            }
            #pragma unroll
            for (int r = 0; r < 4; ++r) {
                float v = mx[r];
                v = fmaxf(v, __shfl_xor(v, 1));
                v = fmaxf(v, __shfl_xor(v, 2));
                v = fmaxf(v, __shfl_xor(v, 4));
                v = fmaxf(v, __shfl_xor(v, 8));
                mx[r] = v;
            }
            float alpha[4], rsum[4];
            #pragma unroll
            for (int r = 0; r < 4; ++r) {
                const float mnew = fmaxf(m_i[h][r], mx[r]);
                alpha[r] = __builtin_amdgcn_exp2f(m_i[h][r] - mnew);
                m_i[h][r] = mnew;
                float s = 0.f;
                #pragma unroll
                for (int c = 0; c < 4; ++c) {
                    const float p = __builtin_amdgcn_exp2f(sc[h][c][r] - mnew);
                    sc[h][c][r] = p;
                    s += p;
                }
                rsum[r] = s;
            }
            #pragma unroll
            for (int r = 0; r < 4; ++r) {
                float v = rsum[r];
                v += __shfl_xor(v, 1);
                v += __shfl_xor(v, 2);
                v += __shfl_xor(v, 4);
                v += __shfl_xor(v, 8);
                l_i[h][r] = l_i[h][r] * alpha[r] + v;
            }
            #pragma unroll
            for (int c = 0; c < 4; ++c) {
                ushort* pw = pblob[w][c >> 1];
                const int wo = ((c & 1) * 2 + (l15 >> 3)) * 16;
                #pragma unroll
                for (int r = 0; r < 4; ++r)
                    pw[(wo + q4 * 4 + r) * 8 + (l15 & 7)] = f2bf_rn(sc[h][c][r]);
            }
            asm volatile("s_waitcnt lgkmcnt(0)" ::: "memory");
            pf[h][0] = *(const short8*)(&pblob[w][0][lane * 8]);
            pf[h][1] = *(const short8*)(&pblob[w][1][lane * 8]);
            #pragma unroll
            for (int t = 0; t < 8; ++t)
                #pragma unroll
                for (int r = 0; r < 4; ++r)
                    o_acc[h][t][r] *= alpha[r];
        }
        #pragma unroll
        for (int t = 0; t < 8; ++t) {
            #pragma unroll
            for (int kc = 0; kc < 2; ++kc) {
                short8 vf = *(const short8*)(&vblob[buf][((t * 2 + kc) * 64 + lane) * 8]);
                if (act0) o_acc[0][t] = __builtin_amdgcn_mfma_f32_16x16x32_bf16(pf[0][kc], vf, o_acc[0][t], 0, 0, 0);
                o_acc[1][t] = __builtin_amdgcn_mfma_f32_16x16x32_bf16(pf[1][kc], vf, o_acc[1][t], 0, 0, 0);
            }
        }
        if (more) commit_v(buf ^ 1);
        __syncthreads();
        buf ^= 1;
    }
    #pragma unroll
    for (int h = 0; h < 2; ++h) {
        float inv[4];
        #pragma unroll
        for (int r = 0; r < 4; ++r) inv[r] = __builtin_amdgcn_rcpf(l_i[h][r]);
        #pragma unroll
        for (int t = 0; t < 8; ++t) {
            #pragma unroll
            for (int r = 0; r < 4; ++r) {
                const int rg = row0[h] + q4 * 4 + r;
                O[hb + (size_t)rg * DIM + t * 16 + l15] = o_acc[h][t][r] * inv[r];
            }
        }
    }
}

extern "C" void kernel_launch(void* const* d_in, const int* in_sizes, int n_in,
                              void* d_out, int out_size, void* d_ws, size_t ws_size,
                              hipStream_t stream) {
    const float* q = (const float*)d_in[0];
    const float* k = (const float*)d_in[1];
    const float* v = (const float*)d_in[2];
    float* o = (float*)d_out;

    const size_t QB_BYTES = (size_t)BATCH * HEADS * SEQ * DIM * 2;  // 32 MB each
    if (ws_size >= 3 * QB_BYTES) {
        ushort* Qb = (ushort*)d_ws;
        ushort* Kb = (ushort*)((char*)d_ws + QB_BYTES);
        ushort* Vb = (ushort*)((char*)d_ws + 2 * QB_BYTES);
        convert_qkv<<<dim3(24576), dim3(256), 0, stream>>>(q, k, v, Qb, Kb, Vb);
        dim3 grid(SEQ / QROWS, BATCH * HEADS);
        fa_fwd<<<grid, dim3(256), 0, stream>>>(Qb, Kb, Vb, o);
    } else {
        dim3 grid(SEQ / QROWS, BATCH * HEADS);
        fa_fwd_fb<<<grid, dim3(256), 0, stream>>>(q, k, v, o);
    }
}